// Round 5
// baseline (154.600 us; speedup 1.0000x reference)
//
#include <hip/hip_runtime.h>
#include <hip/hip_bf16.h>

// Shapes (fixed by the problem)
#define NMOVES 4096
#define LW     15
#define DIM    1024
#define VOC    32
#define NROW   480   // VOC * LW distinct (token, position) rows

typedef __attribute__((ext_vector_type(8))) short  short8;   // 8 bf16 (4 VGPRs)
typedef __attribute__((ext_vector_type(4))) float  floatx4;  // MFMA C/D

__device__ __forceinline__ unsigned short f2b(float f) {
  unsigned int x;
  __builtin_memcpy(&x, &f, 4);
  x = x + 0x7FFFu + ((x >> 16) & 1u);  // round-to-nearest-even
  return (unsigned short)(x >> 16);
}

// ---------------------------------------------------------------------------
// K1: E[(t*15+l)][d] = letter_emb[t][d] + pos_emb[l][d]   (480 x 1024, fp32)
// ---------------------------------------------------------------------------
__global__ __launch_bounds__(256) void build_e(
    const float* __restrict__ letter,
    const float* __restrict__ pos,
    float* __restrict__ E) {
  const int r = blockIdx.x;           // 0..479
  const int t = r / LW;
  const int l = r - t * LW;
  const int d = threadIdx.x * 4;      // 256 threads x 4 elems = 1024
  float4 a = *reinterpret_cast<const float4*>(letter + t * DIM + d);
  float4 b = *reinterpret_cast<const float4*>(pos + l * DIM + d);
  float4 o = make_float4(a.x + b.x, a.y + b.y, a.z + b.z, a.w + b.w);
  *reinterpret_cast<float4*>(E + r * DIM + d) = o;
}

// ---------------------------------------------------------------------------
// 64x64-tile A·B^T GEMM core. fp32 inputs, converted to bf16 during LDS
// staging; bf16 MFMA with fp32 accumulate; fp32 output (+ optional bias).
// 256 threads = 4 waves, 2x2 wave grid, each wave 32x32 via 2x2 fragments of
// mfma_f32_16x16x32_bf16. A/B frag: X[m|n=lane&15][k=(lane>>4)*8+j];
// C/D: col=lane&15, row=(lane>>4)*4+reg  (HW-verified m89/m91/m120).
// ---------------------------------------------------------------------------
#define LDK 72   // 64 + 8 bf16 pad: 144 B row stride, 16B-aligned

__device__ __forceinline__ void gemm_core(
    const float* __restrict__ A, const float* __restrict__ B,
    const float* __restrict__ bias,        // may be null
    float* __restrict__ outf,
    int M, int N, int K, int bm0, int bn0,
    unsigned short* lA, unsigned short* lB) {
  const int tid  = threadIdx.x;
  const int lane = tid & 63;
  const int wave = tid >> 6;
  const int wr   = wave >> 1;
  const int wc   = wave & 1;
  const int quad = lane >> 4;
  const int l16  = lane & 15;

  const int srow = tid >> 3;          // staging: 32 rows per pass
  const int scol = (tid & 7) << 3;    // 8 elements per thread

  floatx4 acc[2][2];
#pragma unroll
  for (int i = 0; i < 2; ++i)
#pragma unroll
    for (int j = 0; j < 2; ++j) acc[i][j] = (floatx4){0.f, 0.f, 0.f, 0.f};

  for (int k0 = 0; k0 < K; k0 += 64) {
#pragma unroll
    for (int half = 0; half < 2; ++half) {
      const int r = half * 32 + srow;
      float4 a0 = make_float4(0.f, 0.f, 0.f, 0.f), a1 = a0;
      const int gr = bm0 + r;
      if (gr < M) {
        const float* p = A + (size_t)gr * K + k0 + scol;
        a0 = *reinterpret_cast<const float4*>(p);
        a1 = *reinterpret_cast<const float4*>(p + 4);
      }
      ushort4 pa0, pa1;
      pa0.x = f2b(a0.x); pa0.y = f2b(a0.y); pa0.z = f2b(a0.z); pa0.w = f2b(a0.w);
      pa1.x = f2b(a1.x); pa1.y = f2b(a1.y); pa1.z = f2b(a1.z); pa1.w = f2b(a1.w);
      *reinterpret_cast<ushort4*>(lA + r * LDK + scol)     = pa0;
      *reinterpret_cast<ushort4*>(lA + r * LDK + scol + 4) = pa1;

      float4 b0 = make_float4(0.f, 0.f, 0.f, 0.f), b1 = b0;
      const int gn = bn0 + r;
      if (gn < N) {
        const float* p = B + (size_t)gn * K + k0 + scol;
        b0 = *reinterpret_cast<const float4*>(p);
        b1 = *reinterpret_cast<const float4*>(p + 4);
      }
      ushort4 pb0, pb1;
      pb0.x = f2b(b0.x); pb0.y = f2b(b0.y); pb0.z = f2b(b0.z); pb0.w = f2b(b0.w);
      pb1.x = f2b(b1.x); pb1.y = f2b(b1.y); pb1.z = f2b(b1.z); pb1.w = f2b(b1.w);
      *reinterpret_cast<ushort4*>(lB + r * LDK + scol)     = pb0;
      *reinterpret_cast<ushort4*>(lB + r * LDK + scol + 4) = pb1;
    }
    __syncthreads();
#pragma unroll
    for (int kk = 0; kk < 64; kk += 32) {
      short8 a0 = *reinterpret_cast<const short8*>(lA + (wr * 32 + l16) * LDK + kk + quad * 8);
      short8 a1 = *reinterpret_cast<const short8*>(lA + (wr * 32 + 16 + l16) * LDK + kk + quad * 8);
      short8 b0 = *reinterpret_cast<const short8*>(lB + (wc * 32 + l16) * LDK + kk + quad * 8);
      short8 b1 = *reinterpret_cast<const short8*>(lB + (wc * 32 + 16 + l16) * LDK + kk + quad * 8);
      acc[0][0] = __builtin_amdgcn_mfma_f32_16x16x32_bf16(a0, b0, acc[0][0], 0, 0, 0);
      acc[0][1] = __builtin_amdgcn_mfma_f32_16x16x32_bf16(a0, b1, acc[0][1], 0, 0, 0);
      acc[1][0] = __builtin_amdgcn_mfma_f32_16x16x32_bf16(a1, b0, acc[1][0], 0, 0, 0);
      acc[1][1] = __builtin_amdgcn_mfma_f32_16x16x32_bf16(a1, b1, acc[1][1], 0, 0, 0);
    }
    __syncthreads();
  }

#pragma unroll
  for (int mi = 0; mi < 2; ++mi) {
#pragma unroll
    for (int ni = 0; ni < 2; ++ni) {
      const int gcol = bn0 + wc * 32 + ni * 16 + l16;
      if (gcol >= N) continue;
      const float bval = bias ? bias[gcol] : 0.f;
#pragma unroll
      for (int i = 0; i < 4; ++i) {
        const int grow = bm0 + wr * 32 + mi * 16 + quad * 4 + i;
        if (grow >= M) continue;
        outf[(size_t)grow * N + gcol] = acc[mi][ni][i] + bval;
      }
    }
  }
}

// K2: Q'/K'/V'[480,1024] = E·W^T + b   (z selects q/k/v)
__global__ __launch_bounds__(256) void qkv_gemm(
    const float* __restrict__ E,
    const float* __restrict__ Wq, const float* __restrict__ Wk,
    const float* __restrict__ Wv,
    const float* __restrict__ bq, const float* __restrict__ bk,
    const float* __restrict__ bv,
    float* __restrict__ Qp, float* __restrict__ Kp, float* __restrict__ Vp) {
  __shared__ __attribute__((aligned(16))) unsigned short lA[64 * LDK];
  __shared__ __attribute__((aligned(16))) unsigned short lB[64 * LDK];
  const float* W; const float* bias; float* O;
  if (blockIdx.z == 0)      { W = Wq; bias = bq; O = Qp; }
  else if (blockIdx.z == 1) { W = Wk; bias = bk; O = Kp; }
  else                      { W = Wv; bias = bv; O = Vp; }
  gemm_core(E, W, bias, O, NROW, DIM, DIM,
            blockIdx.x * 64, blockIdx.y * 64, lA, lB);
}

// K3: G[480,480] = Q'·K'^T  (fp32)
__global__ __launch_bounds__(256) void gram_gemm(
    const float* __restrict__ Qp, const float* __restrict__ Kp,
    float* __restrict__ G) {
  __shared__ __attribute__((aligned(16))) unsigned short lA[64 * LDK];
  __shared__ __attribute__((aligned(16))) unsigned short lB[64 * LDK];
  gemm_core(Qp, Kp, nullptr, G, NROW, NROW, DIM,
            blockIdx.x * 64, blockIdx.y * 64, lA, lB);
}

// ---------------------------------------------------------------------------
// K4: per-move attention. One block per move.
// Tokens dtype detected at runtime (int64 little-endian values <32 have all
// odd 32-bit words zero; int32 random tokens don't — P(miss) = 32^-64).
// S[l][j] = G[r_l][r_j]; P = softmax_j(S); w_j = 2*sum_l P[l][j];
// out[m] = sum_j w_j * V'[r_j]   (fp32 out — reference output dtype)
// ---------------------------------------------------------------------------
__global__ __launch_bounds__(256) void attn_out_k(
    const void* __restrict__ tokens_raw, const float* __restrict__ G,
    const float* __restrict__ Vp, float* __restrict__ out) {
  __shared__ int   ridx[LW];
  __shared__ float S[LW][16];
  __shared__ float w[16];
  __shared__ int   is64_s;
  const int m = blockIdx.x;
  const int tid = threadIdx.x;

  const unsigned int* u32 = (const unsigned int*)tokens_raw;
  if (tid < 64) {  // wave 0: sample odd words tokens32[1,3,...,127]
    unsigned int v = u32[2 * tid + 1];
    unsigned long long nz = __ballot(v != 0);
    if (tid == 0) is64_s = (nz == 0ULL) ? 1 : 0;
  }
  __syncthreads();

  if (tid < LW) {
    int t;
    if (is64_s) t = (int)((const long long*)tokens_raw)[m * LW + tid];
    else        t = ((const int*)tokens_raw)[m * LW + tid];
    ridx[tid] = t * LW + tid;
  }
  __syncthreads();

  if (tid < LW * LW) {
    const int l = tid / LW;
    const int j = tid - l * LW;
    S[l][j] = G[(size_t)ridx[l] * NROW + ridx[j]];
  }
  __syncthreads();

  if (tid < LW) {  // row softmax (over j)
    float mx = -1e30f;
#pragma unroll
    for (int j = 0; j < LW; ++j) mx = fmaxf(mx, S[tid][j]);
    float s = 0.f;
#pragma unroll
    for (int j = 0; j < LW; ++j) { float e = __expf(S[tid][j] - mx); S[tid][j] = e; s += e; }
    const float inv = 1.0f / s;
#pragma unroll
    for (int j = 0; j < LW; ++j) S[tid][j] *= inv;
  }
  __syncthreads();

  if (tid < LW) {  // column weights, with the 2x folded in
    float s = 0.f;
#pragma unroll
    for (int l = 0; l < LW; ++l) s += S[l][tid];
    w[tid] = 2.0f * s;
  }
  __syncthreads();

  const int e0 = tid * 4;  // 256 threads x 4 = 1024 outputs
  float a0 = 0.f, a1 = 0.f, a2 = 0.f, a3 = 0.f;
#pragma unroll
  for (int j = 0; j < LW; ++j) {
    const float wj = w[j];
    float4 vv = *reinterpret_cast<const float4*>(Vp + (size_t)ridx[j] * DIM + e0);
    a0 += wj * vv.x;
    a1 += wj * vv.y;
    a2 += wj * vv.z;
    a3 += wj * vv.w;
  }
  *reinterpret_cast<float4*>(out + (size_t)m * DIM + e0) =
      make_float4(a0, a1, a2, a3);
}

// ---------------------------------------------------------------------------
extern "C" void kernel_launch(void* const* d_in, const int* in_sizes, int n_in,
                              void* d_out, int out_size, void* d_ws, size_t ws_size,
                              hipStream_t stream) {
  const void*  tokens = d_in[0];
  const float* letter = (const float*)d_in[1];
  const float* pos    = (const float*)d_in[2];
  const float* Wq     = (const float*)d_in[3];
  const float* bq     = (const float*)d_in[4];
  const float* Wk     = (const float*)d_in[5];
  const float* bk     = (const float*)d_in[6];
  const float* Wv     = (const float*)d_in[7];
  const float* bv     = (const float*)d_in[8];
  float*       outp   = (float*)d_out;   // reference output dtype = float32

  char* ws = (char*)d_ws;
  const size_t SZ = (size_t)NROW * DIM * 4;  // 1.97 MB per fp32 [480,1024] buffer
  float* E  = (float*)(ws);
  float* Qp = (float*)(ws + SZ);
  float* Kp = (float*)(ws + 2 * SZ);
  float* Vp = (float*)(ws + 3 * SZ);
  float* G  = (float*)(ws + 4 * SZ);         // 480*480*4 = 921600 B

  build_e<<<NROW, 256, 0, stream>>>(letter, pos, E);
  qkv_gemm<<<dim3(8, 16, 3), 256, 0, stream>>>(E, Wq, Wk, Wv, bq, bk, bv, Qp, Kp, Vp);
  gram_gemm<<<dim3(8, 8), 256, 0, stream>>>(Qp, Kp, G);
  attn_out_k<<<NMOVES, 256, 0, stream>>>(tokens, G, Vp, outp);
}

// Round 6
// 149.768 us; speedup vs baseline: 1.0323x; 1.0323x over previous
//
#include <hip/hip_runtime.h>
#include <hip/hip_bf16.h>

// Shapes (fixed by the problem)
#define NMOVES 4096
#define LW     15
#define DIM    1024
#define VOC    32
#define NROW   480   // VOC * LW distinct (token, position) rows

#define GSPLIT 4            // gram K-split factor
#define KSEG   (DIM/GSPLIT) // 256

typedef __attribute__((ext_vector_type(8))) short  short8;   // 8 bf16 (4 VGPRs)
typedef __attribute__((ext_vector_type(4))) float  floatx4;  // MFMA C/D

__device__ __forceinline__ unsigned short f2b(float f) {
  unsigned int x;
  __builtin_memcpy(&x, &f, 4);
  x = x + 0x7FFFu + ((x >> 16) & 1u);  // round-to-nearest-even
  return (unsigned short)(x >> 16);
}
__device__ __forceinline__ ushort4 cvt4(float4 v) {
  ushort4 o; o.x = f2b(v.x); o.y = f2b(v.y); o.z = f2b(v.z); o.w = f2b(v.w);
  return o;
}

#define LDK 72   // 64 + 8 bf16 pad: 144 B row stride, 16B-aligned

// ---------------------------------------------------------------------------
// K1: fused E-build + QKV projection. C[480,1024] = (letter[t]+pos[l])·W^T + b
// E is never materialized: staging adds letter/pos rows on the fly.
// 64x64 tile, 256 thr = 4 waves (2x2), wave does 32x32 via 2x2 fragments of
// mfma_f32_16x16x32_bf16 (fp32 acc). Layouts HW-verified (m89/m91/m120).
// ---------------------------------------------------------------------------
__global__ __launch_bounds__(256) void qkv_fused(
    const float* __restrict__ letter, const float* __restrict__ pos,
    const float* __restrict__ Wq, const float* __restrict__ Wk,
    const float* __restrict__ Wv,
    const float* __restrict__ bq, const float* __restrict__ bk,
    const float* __restrict__ bv,
    float* __restrict__ Qp, float* __restrict__ Kp, float* __restrict__ Vp) {
  __shared__ __attribute__((aligned(16))) unsigned short lA[64 * LDK];
  __shared__ __attribute__((aligned(16))) unsigned short lB[64 * LDK];

  const float* W; const float* bias; float* O;
  if (blockIdx.z == 0)      { W = Wq; bias = bq; O = Qp; }
  else if (blockIdx.z == 1) { W = Wk; bias = bk; O = Kp; }
  else                      { W = Wv; bias = bv; O = Vp; }

  const int bm0 = blockIdx.x * 64;   // row tile (0..7: rows 448..511 guarded)
  const int bn0 = blockIdx.y * 64;   // col tile (0..15)

  const int tid  = threadIdx.x;
  const int lane = tid & 63;
  const int wave = tid >> 6;
  const int wr   = wave >> 1;
  const int wc   = wave & 1;
  const int quad = lane >> 4;
  const int l16  = lane & 15;

  const int srow = tid >> 3;          // staging: 32 rows per half-pass
  const int scol = (tid & 7) << 3;    // 8 floats per thread

  // Per-thread A-row sources, fixed across the K-loop.
  const float* arow[2]; bool aval[2];
#pragma unroll
  for (int half = 0; half < 2; ++half) {
    const int gr = bm0 + half * 32 + srow;
    aval[half] = (gr < NROW);
    const int t = gr / LW;
    const int l = gr - t * LW;
    arow[half] = nullptr;
    if (aval[half]) arow[half] = letter + (size_t)t * DIM;   // + pos row l
    // store l via pointer pair: keep pos row ptr too
  }
  const float* prow[2];
#pragma unroll
  for (int half = 0; half < 2; ++half) {
    const int gr = bm0 + half * 32 + srow;
    const int t = gr / LW;
    const int l = gr - t * LW;
    prow[half] = pos + (size_t)l * DIM;
  }

  floatx4 acc[2][2];
#pragma unroll
  for (int i = 0; i < 2; ++i)
#pragma unroll
    for (int j = 0; j < 2; ++j) acc[i][j] = (floatx4){0.f, 0.f, 0.f, 0.f};

  for (int k0 = 0; k0 < DIM; k0 += 64) {
#pragma unroll
    for (int half = 0; half < 2; ++half) {
      const int r = half * 32 + srow;
      float4 a0 = make_float4(0.f, 0.f, 0.f, 0.f), a1 = a0;
      if (aval[half]) {
        const float* la = arow[half] + k0 + scol;
        const float* lp = prow[half] + k0 + scol;
        float4 x0 = *reinterpret_cast<const float4*>(la);
        float4 x1 = *reinterpret_cast<const float4*>(la + 4);
        float4 p0 = *reinterpret_cast<const float4*>(lp);
        float4 p1 = *reinterpret_cast<const float4*>(lp + 4);
        a0 = make_float4(x0.x + p0.x, x0.y + p0.y, x0.z + p0.z, x0.w + p0.w);
        a1 = make_float4(x1.x + p1.x, x1.y + p1.y, x1.z + p1.z, x1.w + p1.w);
      }
      *reinterpret_cast<ushort4*>(lA + r * LDK + scol)     = cvt4(a0);
      *reinterpret_cast<ushort4*>(lA + r * LDK + scol + 4) = cvt4(a1);

      const int gn = bn0 + r;   // always < 1024
      const float* p = W + (size_t)gn * DIM + k0 + scol;
      float4 b0 = *reinterpret_cast<const float4*>(p);
      float4 b1 = *reinterpret_cast<const float4*>(p + 4);
      *reinterpret_cast<ushort4*>(lB + r * LDK + scol)     = cvt4(b0);
      *reinterpret_cast<ushort4*>(lB + r * LDK + scol + 4) = cvt4(b1);
    }
    __syncthreads();
#pragma unroll
    for (int kk = 0; kk < 64; kk += 32) {
      short8 a0 = *reinterpret_cast<const short8*>(lA + (wr * 32 + l16) * LDK + kk + quad * 8);
      short8 a1 = *reinterpret_cast<const short8*>(lA + (wr * 32 + 16 + l16) * LDK + kk + quad * 8);
      short8 b0 = *reinterpret_cast<const short8*>(lB + (wc * 32 + l16) * LDK + kk + quad * 8);
      short8 b1 = *reinterpret_cast<const short8*>(lB + (wc * 32 + 16 + l16) * LDK + kk + quad * 8);
      acc[0][0] = __builtin_amdgcn_mfma_f32_16x16x32_bf16(a0, b0, acc[0][0], 0, 0, 0);
      acc[0][1] = __builtin_amdgcn_mfma_f32_16x16x32_bf16(a0, b1, acc[0][1], 0, 0, 0);
      acc[1][0] = __builtin_amdgcn_mfma_f32_16x16x32_bf16(a1, b0, acc[1][0], 0, 0, 0);
      acc[1][1] = __builtin_amdgcn_mfma_f32_16x16x32_bf16(a1, b1, acc[1][1], 0, 0, 0);
    }
    __syncthreads();
  }

#pragma unroll
  for (int mi = 0; mi < 2; ++mi) {
#pragma unroll
    for (int ni = 0; ni < 2; ++ni) {
      const int gcol = bn0 + wc * 32 + ni * 16 + l16;
      const float bval = bias[gcol];
#pragma unroll
      for (int i = 0; i < 4; ++i) {
        const int grow = bm0 + wr * 32 + mi * 16 + quad * 4 + i;
        if (grow >= NROW) continue;
        O[(size_t)grow * DIM + gcol] = acc[mi][ni][i] + bval;
      }
    }
  }
}

// ---------------------------------------------------------------------------
// K2: Gram partials. Gpart[p][480,480] = Q'·K'^T over K-segment p (256 wide).
// Grid 8x8x4 = 256 blocks, 4 K-iters each (4x shorter critical path).
// ---------------------------------------------------------------------------
__global__ __launch_bounds__(256) void gram_split(
    const float* __restrict__ Qp, const float* __restrict__ Kp,
    float* __restrict__ Gpart) {
  __shared__ __attribute__((aligned(16))) unsigned short lA[64 * LDK];
  __shared__ __attribute__((aligned(16))) unsigned short lB[64 * LDK];

  const int bm0 = blockIdx.x * 64;
  const int bn0 = blockIdx.y * 64;
  const int kbase = blockIdx.z * KSEG;
  float* Gout = Gpart + (size_t)blockIdx.z * NROW * NROW;

  const int tid  = threadIdx.x;
  const int lane = tid & 63;
  const int wave = tid >> 6;
  const int wr   = wave >> 1;
  const int wc   = wave & 1;
  const int quad = lane >> 4;
  const int l16  = lane & 15;
  const int srow = tid >> 3;
  const int scol = (tid & 7) << 3;

  floatx4 acc[2][2];
#pragma unroll
  for (int i = 0; i < 2; ++i)
#pragma unroll
    for (int j = 0; j < 2; ++j) acc[i][j] = (floatx4){0.f, 0.f, 0.f, 0.f};

  for (int k0 = kbase; k0 < kbase + KSEG; k0 += 64) {
#pragma unroll
    for (int half = 0; half < 2; ++half) {
      const int r = half * 32 + srow;
      float4 a0 = make_float4(0.f, 0.f, 0.f, 0.f), a1 = a0;
      const int gr = bm0 + r;
      if (gr < NROW) {
        const float* p = Qp + (size_t)gr * DIM + k0 + scol;
        a0 = *reinterpret_cast<const float4*>(p);
        a1 = *reinterpret_cast<const float4*>(p + 4);
      }
      *reinterpret_cast<ushort4*>(lA + r * LDK + scol)     = cvt4(a0);
      *reinterpret_cast<ushort4*>(lA + r * LDK + scol + 4) = cvt4(a1);

      float4 b0 = make_float4(0.f, 0.f, 0.f, 0.f), b1 = b0;
      const int gn = bn0 + r;
      if (gn < NROW) {
        const float* p = Kp + (size_t)gn * DIM + k0 + scol;
        b0 = *reinterpret_cast<const float4*>(p);
        b1 = *reinterpret_cast<const float4*>(p + 4);
      }
      *reinterpret_cast<ushort4*>(lB + r * LDK + scol)     = cvt4(b0);
      *reinterpret_cast<ushort4*>(lB + r * LDK + scol + 4) = cvt4(b1);
    }
    __syncthreads();
#pragma unroll
    for (int kk = 0; kk < 64; kk += 32) {
      short8 a0 = *reinterpret_cast<const short8*>(lA + (wr * 32 + l16) * LDK + kk + quad * 8);
      short8 a1 = *reinterpret_cast<const short8*>(lA + (wr * 32 + 16 + l16) * LDK + kk + quad * 8);
      short8 b0 = *reinterpret_cast<const short8*>(lB + (wc * 32 + l16) * LDK + kk + quad * 8);
      short8 b1 = *reinterpret_cast<const short8*>(lB + (wc * 32 + 16 + l16) * LDK + kk + quad * 8);
      acc[0][0] = __builtin_amdgcn_mfma_f32_16x16x32_bf16(a0, b0, acc[0][0], 0, 0, 0);
      acc[0][1] = __builtin_amdgcn_mfma_f32_16x16x32_bf16(a0, b1, acc[0][1], 0, 0, 0);
      acc[1][0] = __builtin_amdgcn_mfma_f32_16x16x32_bf16(a1, b0, acc[1][0], 0, 0, 0);
      acc[1][1] = __builtin_amdgcn_mfma_f32_16x16x32_bf16(a1, b1, acc[1][1], 0, 0, 0);
    }
    __syncthreads();
  }

#pragma unroll
  for (int mi = 0; mi < 2; ++mi) {
#pragma unroll
    for (int ni = 0; ni < 2; ++ni) {
      const int gcol = bn0 + wc * 32 + ni * 16 + l16;
      if (gcol >= NROW) continue;
#pragma unroll
      for (int i = 0; i < 4; ++i) {
        const int grow = bm0 + wr * 32 + mi * 16 + quad * 4 + i;
        if (grow >= NROW) continue;
        Gout[(size_t)grow * NROW + gcol] = acc[mi][ni][i];
      }
    }
  }
}

// ---------------------------------------------------------------------------
// K3: per-move attention. One block per move. Tokens dtype auto-detected.
// S[l][j] = sum_p Gpart[p][r_l,r_j]; P = softmax_j(S); w_j = 2*sum_l P[l][j];
// out[m] = sum_j w_j * V'[r_j]   (fp32 out)
// ---------------------------------------------------------------------------
__global__ __launch_bounds__(256) void attn_out_k(
    const void* __restrict__ tokens_raw, const float* __restrict__ Gpart,
    const float* __restrict__ Vp, float* __restrict__ out) {
  __shared__ int   ridx[LW];
  __shared__ float S[LW][16];
  __shared__ float w[16];
  __shared__ int   is64_s;
  const int m = blockIdx.x;
  const int tid = threadIdx.x;

  const unsigned int* u32 = (const unsigned int*)tokens_raw;
  if (tid < 64) {  // int64 tokens (<32) have all odd 32-bit words zero
    unsigned int v = u32[2 * tid + 1];
    unsigned long long nz = __ballot(v != 0);
    if (tid == 0) is64_s = (nz == 0ULL) ? 1 : 0;
  }
  __syncthreads();

  if (tid < LW) {
    int t;
    if (is64_s) t = (int)((const long long*)tokens_raw)[m * LW + tid];
    else        t = ((const int*)tokens_raw)[m * LW + tid];
    ridx[tid] = t * LW + tid;
  }
  __syncthreads();

  if (tid < LW * LW) {
    const int l = tid / LW;
    const int j = tid - l * LW;
    const size_t off = (size_t)ridx[l] * NROW + ridx[j];
    float s = 0.f;
#pragma unroll
    for (int p = 0; p < GSPLIT; ++p) s += Gpart[(size_t)p * NROW * NROW + off];
    S[l][j] = s;
  }
  __syncthreads();

  if (tid < LW) {  // row softmax (over j)
    float mx = -1e30f;
#pragma unroll
    for (int j = 0; j < LW; ++j) mx = fmaxf(mx, S[tid][j]);
    float s = 0.f;
#pragma unroll
    for (int j = 0; j < LW; ++j) { float e = __expf(S[tid][j] - mx); S[tid][j] = e; s += e; }
    const float inv = 1.0f / s;
#pragma unroll
    for (int j = 0; j < LW; ++j) S[tid][j] *= inv;
  }
  __syncthreads();

  if (tid < LW) {  // column weights, with the 2x folded in
    float s = 0.f;
#pragma unroll
    for (int l = 0; l < LW; ++l) s += S[l][tid];
    w[tid] = 2.0f * s;
  }
  __syncthreads();

  const int e0 = tid * 4;  // 256 threads x 4 = 1024 outputs
  float a0 = 0.f, a1 = 0.f, a2 = 0.f, a3 = 0.f;
#pragma unroll
  for (int j = 0; j < LW; ++j) {
    const float wj = w[j];
    float4 vv = *reinterpret_cast<const float4*>(Vp + (size_t)ridx[j] * DIM + e0);
    a0 += wj * vv.x;
    a1 += wj * vv.y;
    a2 += wj * vv.z;
    a3 += wj * vv.w;
  }
  *reinterpret_cast<float4*>(out + (size_t)m * DIM + e0) =
      make_float4(a0, a1, a2, a3);
}

// ---------------------------------------------------------------------------
extern "C" void kernel_launch(void* const* d_in, const int* in_sizes, int n_in,
                              void* d_out, int out_size, void* d_ws, size_t ws_size,
                              hipStream_t stream) {
  const void*  tokens = d_in[0];
  const float* letter = (const float*)d_in[1];
  const float* pos    = (const float*)d_in[2];
  const float* Wq     = (const float*)d_in[3];
  const float* bq     = (const float*)d_in[4];
  const float* Wk     = (const float*)d_in[5];
  const float* bk     = (const float*)d_in[6];
  const float* Wv     = (const float*)d_in[7];
  const float* bv     = (const float*)d_in[8];
  float*       outp   = (float*)d_out;   // reference output dtype = float32

  char* ws = (char*)d_ws;
  const size_t SZ = (size_t)NROW * DIM * 4;       // 1.97 MB per [480,1024] fp32
  float* Qp = (float*)(ws);
  float* Kp = (float*)(ws + SZ);
  float* Vp = (float*)(ws + 2 * SZ);
  float* Gp = (float*)(ws + 3 * SZ);              // 4 x 480*480*4 = 3.7 MB

  qkv_fused<<<dim3(8, 16, 3), 256, 0, stream>>>(letter, pos, Wq, Wk, Wv,
                                                bq, bk, bv, Qp, Kp, Vp);
  gram_split<<<dim3(8, 8, GSPLIT), 256, 0, stream>>>(Qp, Kp, Gp);
  attn_out_k<<<NMOVES, 256, 0, stream>>>(tokens, Gp, Vp, outp);
}